// Round 8
// baseline (480.942 us; speedup 1.0000x reference)
//
#include <hip/hip_runtime.h>
#include <hip/hip_bf16.h>

// Problem: B=4, T=2048, DIM=1024, H=16, DH=64.  fp32 in/out, bf16 MFMA inside.
// qkv col n = d*48 + kk*16 + h (d outermost, h innermost).

typedef __attribute__((ext_vector_type(8))) short short8;
typedef __attribute__((ext_vector_type(4))) float floatx4;

static __device__ __forceinline__ floatx4 mfma16(short8 a, short8 b, floatx4 c) {
    return __builtin_amdgcn_mfma_f32_16x16x32_bf16(a, b, c, 0, 0, 0);
}

static __device__ __forceinline__ unsigned short f2bf_bits(float f) {
    __hip_bfloat16 h = __float2bfloat16(f);
    return *reinterpret_cast<unsigned short*>(&h);
}

static __device__ __forceinline__ float fast_exp2(float x) {
#if __has_builtin(__builtin_amdgcn_exp2f)
    return __builtin_amdgcn_exp2f(x);
#else
    return exp2f(x);
#endif
}

// async global->LDS, 16 B per lane; LDS dest = wave-uniform base + lane*16
#define GLD16(gptr, ldsptr)                                                  \
    __builtin_amdgcn_global_load_lds(                                        \
        (const __attribute__((address_space(1))) void*)(gptr),               \
        (__attribute__((address_space(3))) void*)(ldsptr), 16, 0, 0)

// ---------------------------------------------------------------------------
// Kernel 0: fp32 -> bf16 conversion
// ---------------------------------------------------------------------------
__global__ __launch_bounds__(256) void k_cvt(
    const float* __restrict__ src, unsigned short* __restrict__ dst, int n4)
{
    typedef __attribute__((ext_vector_type(4))) unsigned short ushort4v;
    for (int i = blockIdx.x * blockDim.x + threadIdx.x; i < n4;
         i += gridDim.x * blockDim.x) {
        const float4 v = ((const float4*)src)[i];
        ushort4v o;
        o.x = f2bf_bits(v.x);
        o.y = f2bf_bits(v.y);
        o.z = f2bf_bits(v.z);
        o.w = f2bf_bits(v.w);
        ((ushort4v*)dst)[i] = o;
    }
}

// ---------------------------------------------------------------------------
// Kernel 1: QKV projection, global_load_lds staging.  Outputs [b][h][d][t],
// ushort4 packed stores.  q pre-scaled by log2(e)/32.
// ---------------------------------------------------------------------------
__global__ __launch_bounds__(256) void k_qkv(
    const unsigned short* __restrict__ x,   // [8192][1024] bf16
    const unsigned short* __restrict__ wq,  // [3072][1024] bf16
    unsigned short* __restrict__ qb,        // [4][16][64][2048]
    unsigned short* __restrict__ kb,        // [4][16][64][2048]
    unsigned short* __restrict__ vb)        // [4][16][64][2048]
{
    __shared__ unsigned short As[128 * 32];
    __shared__ unsigned short Bs[128 * 32];

    const int tid  = threadIdx.x;
    const int wave = tid >> 6, lane = tid & 63;
    const int quad = lane >> 4, l16 = lane & 15;
    const int wm = wave >> 1, wn = wave & 1;
    const int m0 = blockIdx.y * 128;
    const int kk = blockIdx.x >> 3;
    const int d0 = (blockIdx.x & 7) * 8;
    const int kkh = kk * 16;

    const int srow = lane >> 2;          // 0..15
    const int sc8  = (lane & 3) * 8;     // 0,8,16,24
    const int row0 = wave * 32 + srow;
    const int row1 = row0 + 16;
    const int bn0  = (d0 + (row0 >> 4)) * 48 + kkh + (row0 & 15);
    const int bn1  = (d0 + (row1 >> 4)) * 48 + kkh + (row1 & 15);

    floatx4 acc[4][4];
#pragma unroll
    for (int i = 0; i < 4; i++)
#pragma unroll
        for (int j = 0; j < 4; j++) acc[i][j] = (floatx4){0.f, 0.f, 0.f, 0.f};

    for (int k0 = 0; k0 < 1024; k0 += 32) {
        GLD16(&x[(m0 + row0) * 1024 + k0 + sc8], &As[(wave * 32) * 32]);
        GLD16(&x[(m0 + row1) * 1024 + k0 + sc8], &As[(wave * 32 + 16) * 32]);
        GLD16(&wq[bn0 * 1024 + k0 + sc8],        &Bs[(wave * 32) * 32]);
        GLD16(&wq[bn1 * 1024 + k0 + sc8],        &Bs[(wave * 32 + 16) * 32]);
        __syncthreads();

        short8 af[4], bfv[4];
#pragma unroll
        for (int mi = 0; mi < 4; mi++)
            af[mi] = *(const short8*)&As[(wm * 64 + mi * 16 + l16) * 32 + quad * 8];
#pragma unroll
        for (int ni = 0; ni < 4; ni++)
            bfv[ni] = *(const short8*)&Bs[(wn * 64 + ni * 16 + l16) * 32 + quad * 8];
#pragma unroll
        for (int mi = 0; mi < 4; mi++)
#pragma unroll
            for (int ni = 0; ni < 4; ni++)
                acc[mi][ni] = mfma16(af[mi], bfv[ni], acc[mi][ni]);
        __syncthreads();
    }

    unsigned short* dst = (kk == 0) ? qb : (kk == 1) ? kb : vb;
    const float scale = (kk == 0) ? 0.045084220027780106f : 1.0f;  // log2(e)/32
#pragma unroll
    for (int ni = 0; ni < 4; ni++) {
        const int d = d0 + wn * 4 + ni;
#pragma unroll
        for (int mi = 0; mi < 4; mi++) {
            const int m  = m0 + wm * 64 + mi * 16 + quad * 4;
            const int b  = m >> 11;
            const int tt = m & 2047;
            ushort4 pk;
            pk.x = f2bf_bits(acc[mi][ni][0] * scale);
            pk.y = f2bf_bits(acc[mi][ni][1] * scale);
            pk.z = f2bf_bits(acc[mi][ni][2] * scale);
            pk.w = f2bf_bits(acc[mi][ni][3] * scale);
            *(ushort4*)&dst[((b * 16 + l16) * 64 + d) * 2048 + tt] = pk;
        }
    }
}

// ---------------------------------------------------------------------------
// Kernel 1b: transpose [bh][64 d][2048 t] -> [bh][2048 t][64 d].
// ---------------------------------------------------------------------------
__global__ __launch_bounds__(256) void k_tr(
    const unsigned short* __restrict__ src,
    unsigned short* __restrict__ dst)
{
    __shared__ unsigned short Ts[64 * 72];
    const int tid = threadIdx.x;
    const int bh  = blockIdx.y;
    const int t0  = blockIdx.x * 64;
    const int dg  = (tid >> 4) * 4;
    const int tg  = (tid & 15) * 4;

    ushort4 rv[4];
#pragma unroll
    for (int dd = 0; dd < 4; dd++)
        rv[dd] = *(const ushort4*)&src[(bh * 64 + dg + dd) * 2048 + t0 + tg];
#pragma unroll
    for (int tt = 0; tt < 4; tt++) {
        ushort4 wv;
        wv.x = ((const unsigned short*)&rv[0])[tt];
        wv.y = ((const unsigned short*)&rv[1])[tt];
        wv.z = ((const unsigned short*)&rv[2])[tt];
        wv.w = ((const unsigned short*)&rv[3])[tt];
        *(ushort4*)&Ts[(tg + tt) * 72 + dg] = wv;
    }
    __syncthreads();

    const int tr = tid >> 2;
    const int c8 = (tid & 3) * 8;
    *(uint4*)&dst[(bh * 2048 + t0 + tr) * 64 + c8]      = *(const uint4*)&Ts[tr * 72 + c8];
    *(uint4*)&dst[(bh * 2048 + t0 + tr) * 64 + c8 + 32] = *(const uint4*)&Ts[tr * 72 + c8 + 32];
}

// ---------------------------------------------------------------------------
// Kernel 2: flash attention, BARRIER-FREE.  256 threads / 4 waves; wave owns
// 32 q-rows.  K and V fragments loaded DIRECTLY from global in MFMA layout
// (16B coalesced; all co-bh waves/blocks read identical addresses -> L1/L2
// broadcast).  Only P round-trips through wave-private LDS; no __syncthreads
// in the whole kernel -> compiler pipelines next-iter K/V loads over PV.
// S^T = K*Q^T form (C-quartet = 4 consecutive keys -> packed b64 Pt writes).
// Fixed-max softmax in exp2 domain (q carries log2e/32).  XCD-affine grid.
// ---------------------------------------------------------------------------
__global__ __launch_bounds__(256) void k_attn(
    const unsigned short* __restrict__ qt,  // [64][2048][64]  (bh, t, d)
    const unsigned short* __restrict__ kt,  // [64][2048][64]
    const unsigned short* __restrict__ vg,  // [64][64][2048]  (bh, d, t)
    __hip_bfloat16* __restrict__ og)        // [4][2048][1024]
{
    __shared__ unsigned short Pt[4 * 32 * 72];  // wave-private 32 rows each

    const int tid  = threadIdx.x;
    const int wave = tid >> 6, lane = tid & 63;
    const int quad = lane >> 4, l16 = lane & 15;
    const int blk = blockIdx.x;
    const int bh  = (blk & 7) | ((blk >> 7) << 3);  // bh%8 == blk%8 (XCD-affine)
    const int q0  = ((blk >> 3) & 15) * 128;
    const int qr  = q0 + wave * 32;

    const unsigned short* kbase = kt + bh * 2048 * 64;
    const unsigned short* vbase = vg + bh * 64 * 2048;

    // Q fragments (B-operand layout), resident for the whole kernel
    short8 qf[2][2];
#pragma unroll
    for (int mi = 0; mi < 2; mi++)
#pragma unroll
        for (int ks = 0; ks < 2; ks++)
            qf[mi][ks] = *(const short8*)&qt[(bh * 2048 + qr + mi * 16 + l16) * 64 + ks * 32 + quad * 8];

    float lsum[2] = {0.f, 0.f};
    floatx4 o[2][4];
#pragma unroll
    for (int mi = 0; mi < 2; mi++)
#pragma unroll
        for (int di = 0; di < 4; di++) o[mi][di] = (floatx4){0.f, 0.f, 0.f, 0.f};

    for (int j0 = 0; j0 < 2048; j0 += 64) {
        // K fragments direct from global: A[m=key][k=d]
        short8 kf[2][4];
#pragma unroll
        for (int ks = 0; ks < 2; ks++)
#pragma unroll
            for (int nk = 0; nk < 4; nk++)
                kf[ks][nk] = *(const short8*)&kbase[(j0 + nk * 16 + l16) * 64 + ks * 32 + quad * 8];

        // S^T = K Q^T: D[m=key][n=qrow]
        floatx4 st[2][4];
#pragma unroll
        for (int mi = 0; mi < 2; mi++)
#pragma unroll
            for (int nk = 0; nk < 4; nk++) st[mi][nk] = (floatx4){0.f, 0.f, 0.f, 0.f};
#pragma unroll
        for (int ks = 0; ks < 2; ks++)
#pragma unroll
            for (int mi = 0; mi < 2; mi++)
#pragma unroll
                for (int nk = 0; nk < 4; nk++)
                    st[mi][nk] = mfma16(kf[ks][nk], qf[mi][ks], st[mi][nk]);

        // p = 2^s; quartet = 4 consecutive keys at qrow=l16 -> packed b64 write
#pragma unroll
        for (int mi = 0; mi < 2; mi++) {
#pragma unroll
            for (int nk = 0; nk < 4; nk++) {
                const float p0 = fast_exp2(st[mi][nk][0]);
                const float p1 = fast_exp2(st[mi][nk][1]);
                const float p2 = fast_exp2(st[mi][nk][2]);
                const float p3 = fast_exp2(st[mi][nk][3]);
                lsum[mi] += (p0 + p1) + (p2 + p3);
                ushort4 pk;
                pk.x = f2bf_bits(p0);
                pk.y = f2bf_bits(p1);
                pk.z = f2bf_bits(p2);
                pk.w = f2bf_bits(p3);
                *(ushort4*)&Pt[(wave * 32 + mi * 16 + l16) * 72 + nk * 16 + quad * 4] = pk;
            }
        }

        // V fragments direct from global: B[k=key][n=d]
        short8 vf[2][4];
#pragma unroll
        for (int ks = 0; ks < 2; ks++)
#pragma unroll
            for (int di = 0; di < 4; di++)
                vf[ks][di] = *(const short8*)&vbase[(di * 16 + l16) * 2048 + j0 + ks * 32 + quad * 8];

        __builtin_amdgcn_s_waitcnt(0xc07f);  // lgkmcnt(0): wave-local Pt RAW

        short8 pf[2][2];
#pragma unroll
        for (int ks = 0; ks < 2; ks++)
#pragma unroll
            for (int mi = 0; mi < 2; mi++)
                pf[ks][mi] = *(const short8*)&Pt[(wave * 32 + mi * 16 + l16) * 72 + ks * 32 + quad * 8];

        // O += P V
#pragma unroll
        for (int ks = 0; ks < 2; ks++)
#pragma unroll
            for (int mi = 0; mi < 2; mi++)
#pragma unroll
                for (int di = 0; di < 4; di++)
                    o[mi][di] = mfma16(pf[ks][mi], vf[ks][di], o[mi][di]);
    }

    // reduce lsum across quads (keys were quad-partitioned)
#pragma unroll
    for (int mi = 0; mi < 2; mi++) {
        float t = lsum[mi];
        t += __shfl_xor(t, 16);
        t += __shfl_xor(t, 32);
        lsum[mi] = t;
    }

    // epilogue: o / l -> [b][t][h*64+d]
    const int b = bh >> 4, h = bh & 15;
#pragma unroll
    for (int mi = 0; mi < 2; mi++) {
#pragma unroll
        for (int r = 0; r < 4; r++) {
            const float inv = 1.0f / __shfl(lsum[mi], quad * 4 + r);
            const int t = qr + mi * 16 + quad * 4 + r;
#pragma unroll
            for (int di = 0; di < 4; di++)
                og[(b * 2048 + t) * 1024 + h * 64 + di * 16 + l16] =
                    __float2bfloat16(o[mi][di][r] * inv);
        }
    }
}

// ---------------------------------------------------------------------------
// Kernel 3: output projection.  fp32 bias / fp32 out.
// ---------------------------------------------------------------------------
__global__ __launch_bounds__(256) void k_out(
    const unsigned short* __restrict__ a,    // [8192][1024] bf16
    const unsigned short* __restrict__ wq,   // [1024][1024] bf16
    const float* __restrict__ bias,
    float* __restrict__ out)                 // [8192][1024] fp32
{
    __shared__ unsigned short As[128 * 32];
    __shared__ unsigned short Bs[128 * 32];

    const int tid  = threadIdx.x;
    const int wave = tid >> 6, lane = tid & 63;
    const int quad = lane >> 4, l16 = lane & 15;
    const int wm = wave >> 1, wn = wave & 1;
    const int m0 = blockIdx.y * 128, n0 = blockIdx.x * 128;

    const int srow = lane >> 2;
    const int sc8  = (lane & 3) * 8;
    const int row0 = wave * 32 + srow;
    const int row1 = row0 + 16;

    floatx4 acc[4][4];
#pragma unroll
    for (int i = 0; i < 4; i++)
#pragma unroll
        for (int j = 0; j < 4; j++) acc[i][j] = (floatx4){0.f, 0.f, 0.f, 0.f};

    for (int k0 = 0; k0 < 1024; k0 += 32) {
        GLD16(&a[(m0 + row0) * 1024 + k0 + sc8],  &As[(wave * 32) * 32]);
        GLD16(&a[(m0 + row1) * 1024 + k0 + sc8],  &As[(wave * 32 + 16) * 32]);
        GLD16(&wq[(n0 + row0) * 1024 + k0 + sc8], &Bs[(wave * 32) * 32]);
        GLD16(&wq[(n0 + row1) * 1024 + k0 + sc8], &Bs[(wave * 32 + 16) * 32]);
        __syncthreads();

        short8 af[4], bfv[4];
#pragma unroll
        for (int mi = 0; mi < 4; mi++)
            af[mi] = *(const short8*)&As[(wm * 64 + mi * 16 + l16) * 32 + quad * 8];
#pragma unroll
        for (int ni = 0; ni < 4; ni++)
            bfv[ni] = *(const short8*)&Bs[(wn * 64 + ni * 16 + l16) * 32 + quad * 8];
#pragma unroll
        for (int mi = 0; mi < 4; mi++)
#pragma unroll
            for (int ni = 0; ni < 4; ni++)
                acc[mi][ni] = mfma16(af[mi], bfv[ni], acc[mi][ni]);
        __syncthreads();
    }

#pragma unroll
    for (int ni = 0; ni < 4; ni++) {
        const int col = n0 + wn * 64 + ni * 16 + l16;
        const float bv = bias[col];
#pragma unroll
        for (int mi = 0; mi < 4; mi++) {
            const int mbase = m0 + wm * 64 + mi * 16 + quad * 4;
#pragma unroll
            for (int r = 0; r < 4; r++)
                out[(mbase + r) * 1024 + col] = acc[mi][ni][r] + bv;
        }
    }
}

// ---------------------------------------------------------------------------
extern "C" void kernel_launch(void* const* d_in, const int* in_sizes, int n_in,
                              void* d_out, int out_size, void* d_ws, size_t ws_size,
                              hipStream_t stream) {
    const float* x    = (const float*)d_in[0];
    const float* wqkv = (const float*)d_in[1];
    const float* wout = (const float*)d_in[2];
    const float* bout = (const float*)d_in[3];
    float* out = (float*)d_out;

    unsigned short* ws = (unsigned short*)d_ws;
    unsigned short* xb    = ws;                  // x bf16; later reused as q[t][d]
    unsigned short* wqkvb = xb + 8388608;
    unsigned short* woutb = wqkvb + 3145728;
    unsigned short* qb    = woutb + 1048576;     // q [d][t]; later reused as k[t][d]
    unsigned short* kb    = qb + 8388608;        // k [d][t]
    unsigned short* vb    = kb + 8388608;        // v [d][t]
    unsigned short* ob    = vb + 8388608;        // attn out

    k_cvt<<<2048, 256, 0, stream>>>(x,    xb,    8388608 / 4);
    k_cvt<<<1024, 256, 0, stream>>>(wqkv, wqkvb, 3145728 / 4);
    k_cvt<<<512,  256, 0, stream>>>(wout, woutb, 1048576 / 4);

    k_qkv<<<dim3(24, 64), 256, 0, stream>>>(xb, wqkvb, qb, kb, vb);

    // transpose q,k to [bh][t][d]; xb and (then-dead) qb are recycled
    k_tr<<<dim3(32, 64), 256, 0, stream>>>(qb, xb);   // q -> xb
    k_tr<<<dim3(32, 64), 256, 0, stream>>>(kb, qb);   // k -> qb

    k_attn<<<1024, 256, 0, stream>>>(xb, qb, vb, (__hip_bfloat16*)ob);
    k_out<<<dim3(8, 64), 256, 0, stream>>>(ob, woutb, bout, out);
}